// Round 17
// baseline (185.403 us; speedup 1.0000x reference)
//
#include <hip/hip_runtime.h>
#include <hip/hip_bf16.h>

static constexpr int kN   = 4096;
static constexpr int kIn  = 128;
static constexpr int kHid = 512;
static constexpr int kH   = 8;
static constexpr int kD   = 64;

// padded fragment-panel strides (break power-of-2 L2 channel aliasing)
static constexpr int kKFS = 32768 + 64;    // K panel stride (elements)
static constexpr int kVFS = 131072 + 64;   // V panel stride (elements)

// exp2-domain softmax: p = 2^(sc*SCLG2 + tb*LOG2E - m2)
#define LOG2E  1.44269504f
#define SCLG2  0.18033688f      /* 0.125 * LOG2E */
#define MASKL2 (-43281.0f)      /* -30000 * LOG2E, f16-representable */
#define THRL2  11.5415603f      /* 8 * LOG2E */

typedef __bf16    bf16x8 __attribute__((ext_vector_type(8)));
typedef _Float16  f16x8  __attribute__((ext_vector_type(8)));
typedef unsigned short u16x8 __attribute__((ext_vector_type(8)));
typedef float  f32x4  __attribute__((ext_vector_type(4)));
typedef float  f32x16 __attribute__((ext_vector_type(16)));

__device__ __forceinline__ unsigned short f2bf(float f) {
    return __builtin_bit_cast(unsigned short, (__bf16)f);
}
__device__ __forceinline__ unsigned pkbf(float a, float b) {
    return (unsigned)f2bf(a) | ((unsigned)f2bf(b) << 16);
}
__device__ __forceinline__ unsigned short f2h(float f) {
    return __builtin_bit_cast(unsigned short, (_Float16)f);
}
__device__ __forceinline__ float fast_exp2(float x) {
#if __has_builtin(__builtin_amdgcn_exp2f)
    return __builtin_amdgcn_exp2f(x);
#else
    return exp2f(x);
#endif
}

// ---------------- consolidated prep: detect + bc + Wo-transpose + Wct, one launch -------
// blocks 0         : mask dtype detect
// blocks 1..6      : bc[j] = sum_k b_in[k]*Wqkv[k][j] + bqkv[j]
// blocks 7..262    : Wo transpose f32[512][512] -> bf16^T (256 tiles)
// blocks 263..358  : Wct (96 blocks, 8 input-dims per block: W panels read once per
//                    8 i-values instead of per i -> ~8x less L2 traffic)
__global__ __launch_bounds__(256) void prep_kernel(
    const unsigned int* __restrict__ m, int* __restrict__ mode,
    const float* __restrict__ b_in,
    const float* __restrict__ bq, const float* __restrict__ bk, const float* __restrict__ bv,
    const float* __restrict__ Wq, const float* __restrict__ Wk, const float* __restrict__ Wv,
    const float* __restrict__ W_in,
    const float* __restrict__ Wo, unsigned short* __restrict__ Wt_o,
    float* __restrict__ bc, unsigned short* __restrict__ Wct) {
    const int bx = blockIdx.x;
    const int t  = threadIdx.x;
    if (bx == 0) {
        if (t >= 64) return;
        int isf = 0, isb = 0;
        for (int i = t; i < 4096; i += 64) {
            unsigned int w = m[i];
            if (w == 0x3F800000u) isf = 1;
            else if (w > 1u)      isb = 1;
        }
        unsigned long long bf = __ballot(isf != 0);
        unsigned long long bb = __ballot(isb != 0);
        if (t == 0) mode[0] = bf ? 2 : (bb ? 1 : 0);
        return;
    }
    if (bx <= 6) {
        int j = (bx - 1) * 256 + t;   // 0..1535
        const float* W = j < 512 ? Wq : (j < 1024 ? Wk : Wv);
        int jc = j & 511;
        float acc = j < 512 ? bq[jc] : (j < 1024 ? bk[jc] : bv[jc]);
        for (int k = 0; k < kHid; k++) acc = fmaf(b_in[k], W[(size_t)k * kHid + jc], acc);
        bc[j] = acc;
        return;
    }
    if (bx <= 262) {
        __shared__ float tile[32][33];
        int bx2 = bx - 7;
        int c0 = (bx2 & 15) * 32, r0 = (bx2 >> 4) * 32;
        int tx = t & 31, ty = t >> 5;   // 32 x 8
#pragma unroll
        for (int i = 0; i < 4; i++) {
            int r = ty + i * 8;
            tile[r][tx] = Wo[(size_t)(r0 + r) * kHid + c0 + tx];
        }
        __syncthreads();
#pragma unroll
        for (int i = 0; i < 4; i++) {
            int r = ty + i * 8;
            Wt_o[(size_t)(c0 + r) * kHid + r0 + tx] = f2bf(tile[tx][r]);
        }
        return;
    }
    {
        int bx3 = bx - 263;             // 0..95
        int ig = bx3 / 6;               // 0..15: group of 8 input-dims
        int jg = bx3 % 6;               // 0..5
        int j  = jg * 256 + t;          // 0..1535 (lane-consecutive)
        const float* W = j < 512 ? Wq : (j < 1024 ? Wk : Wv);
        int jc = j & 511;
        const int i0 = ig * 8;
        float acc[8] = {};
        for (int k = 0; k < kHid; k++) {
            float wv = W[(size_t)k * kHid + jc];           // coalesced, shared by 8 i
#pragma unroll
            for (int u = 0; u < 8; u++)
                acc[u] = fmaf(W_in[(size_t)(i0 + u) * kHid + k], wv, acc[u]);  // uniform scalar
        }
#pragma unroll
        for (int u = 0; u < 8; u++)
            Wct[(size_t)j * kIn + i0 + u] = f2bf(acc[u]);
    }
}

// ---------------- fused: QKV GEMM (blocks 0..383) + bias compress (blocks 384..8575) ----
__global__ __launch_bounds__(256) void fused_pp_qkv_kernel(
    const float* __restrict__ Anode, const unsigned short* __restrict__ Wct,
    const float* __restrict__ bcv,
    unsigned short* __restrict__ qbp, unsigned short* __restrict__ kfp,
    unsigned short* __restrict__ vfp,
    const void* __restrict__ maskp, const float* __restrict__ tbp,
    const int* __restrict__ modep, unsigned short* __restrict__ bias_c) {
    __shared__ unsigned short As[128][40];
    __shared__ unsigned short Bs[128][40];
    const int b = blockIdx.x;
    if (b >= 384) {
        // ---- prepass branch: (mask, tb) -> f16 log2-domain bias ----
        const int mode = modep[0];
        size_t idx = ((size_t)(b - 384) * 256 + threadIdx.x) * 8;
        float tv[8];
        *(float4*)&tv[0] = *(const float4*)(tbp + idx);
        *(float4*)&tv[4] = *(const float4*)(tbp + idx + 4);
        u16x8 o;
        if (mode == 0) {
            const int* mp = (const int*)maskp;
            int4 a = *(const int4*)(mp + idx);
            int4 bb = *(const int4*)(mp + idx + 4);
            int mv[8] = {a.x, a.y, a.z, a.w, bb.x, bb.y, bb.z, bb.w};
#pragma unroll
            for (int j = 0; j < 8; j++) o[j] = f2h(mv[j] ? MASKL2 : tv[j] * LOG2E);
        } else if (mode == 1) {
            const unsigned char* mp = (const unsigned char*)maskp;
            uint2 u = *(const uint2*)(mp + idx);
#pragma unroll
            for (int j = 0; j < 4; j++) o[j] = f2h(((u.x >> (8 * j)) & 255u) ? MASKL2 : tv[j] * LOG2E);
#pragma unroll
            for (int j = 0; j < 4; j++) o[4 + j] = f2h(((u.y >> (8 * j)) & 255u) ? MASKL2 : tv[4 + j] * LOG2E);
        } else {
            const float* mp = (const float*)maskp;
            float4 a = *(const float4*)(mp + idx);
            float4 bb = *(const float4*)(mp + idx + 4);
            float mv[8] = {a.x, a.y, a.z, a.w, bb.x, bb.y, bb.z, bb.w};
#pragma unroll
            for (int j = 0; j < 8; j++) o[j] = f2h((mv[j] != 0.f) ? MASKL2 : tv[j] * LOG2E);
        }
        *(u16x8*)(bias_c + idx) = o;
        return;
    }
    // ---- QKV GEMM branch: [4096,128] @ Wct^T + bc; M=4096 N=1536 K=128 ----
    const int tid  = threadIdx.x;
    const int lane = tid & 63;
    const int wv   = tid >> 6;
    const int wr   = wv >> 1, wc = wv & 1;
    const int m0 = (b & 31) * 128, n0 = (b >> 5) * 128;
    const int g = lane >> 4, li = lane & 15;
    const int K = kIn;

    f32x4 acc[4][4] = {};
    const int rr = tid >> 2;
    const int cc = (tid & 3) * 8;

    for (int k0 = 0; k0 < K; k0 += 32) {
#pragma unroll
        for (int p = 0; p < 128; p += 64) {
            int r = rr + p;
            const float4 v0 = *(const float4*)(Anode + (size_t)(m0 + r) * K + k0 + cc);
            const float4 v1 = *(const float4*)(Anode + (size_t)(m0 + r) * K + k0 + cc + 4);
            uint4 u;
            u.x = f2bf(v0.x) | ((unsigned)f2bf(v0.y) << 16);
            u.y = f2bf(v0.z) | ((unsigned)f2bf(v0.w) << 16);
            u.z = f2bf(v1.x) | ((unsigned)f2bf(v1.y) << 16);
            u.w = f2bf(v1.z) | ((unsigned)f2bf(v1.w) << 16);
            *(uint4*)&As[r][cc] = u;
            *(uint4*)&Bs[r][cc] = *(const uint4*)(Wct + (size_t)(n0 + r) * K + k0 + cc);
        }
        __syncthreads();

        bf16x8 af[4], bfv[4];
#pragma unroll
        for (int mi = 0; mi < 4; mi++)
            af[mi] = *(const bf16x8*)&As[wr * 64 + mi * 16 + li][g * 8];
#pragma unroll
        for (int ni = 0; ni < 4; ni++)
            bfv[ni] = *(const bf16x8*)&Bs[wc * 64 + ni * 16 + li][g * 8];
#pragma unroll
        for (int mi = 0; mi < 4; mi++)
#pragma unroll
            for (int ni = 0; ni < 4; ni++)
                acc[mi][ni] = __builtin_amdgcn_mfma_f32_16x16x32_bf16(af[mi], bfv[ni], acc[mi][ni], 0, 0, 0);
        __syncthreads();
    }

#pragma unroll
    for (int mi = 0; mi < 4; mi++) {
        int rowb = m0 + wr * 64 + mi * 16 + g * 4;
#pragma unroll
        for (int ni = 0; ni < 4; ni++) {
            int col = n0 + wc * 64 + ni * 16 + li;
            float bv = bcv[col];
            if (col < 512) {
#pragma unroll
                for (int r2 = 0; r2 < 4; r2++)
                    qbp[(size_t)(rowb + r2) * 512 + col] = f2bf(acc[mi][ni][r2] + bv);
            } else if (col < 1024) {
                int d = col - 512;
                size_t base = (size_t)(d >> 3) * kKFS + (size_t)(d & 7);
#pragma unroll
                for (int r2 = 0; r2 < 4; r2++)
                    kfp[base + ((size_t)(rowb + r2) << 3)] = f2bf(acc[mi][ni][r2] + bv);
            } else {
                int d = col - 1024;
                size_t base = (size_t)(d >> 5) * kVFS + ((size_t)(rowb >> 3) << 8) +
                              ((size_t)(d & 31) << 3) + (size_t)(rowb & 7);
                ushort4 st;
                st.x = f2bf(acc[mi][ni][0] + bv);
                st.y = f2bf(acc[mi][ni][1] + bv);
                st.z = f2bf(acc[mi][ni][2] + bv);
                st.w = f2bf(acc[mi][ni][3] + bv);
                *(ushort4*)(vfp + base) = st;
            }
        }
    }
}

// ---------------- GEMM: C[M,N] = A[M,K] @ Bt[N,K]^T + bias (f32 out) ----------------
__global__ __launch_bounds__(256) void gemm_out_kernel(const unsigned short* __restrict__ A,
                                                       const unsigned short* __restrict__ Bt,
                                                       const float* __restrict__ bias,
                                                       float* __restrict__ Cp,
                                                       int M, int K, int ldc) {
    __shared__ unsigned short As[128][40];
    __shared__ unsigned short Bs[128][40];
    const int tid  = threadIdx.x;
    const int lane = tid & 63;
    const int wv   = tid >> 6;
    const int wr   = wv >> 1, wc = wv & 1;
    const int m0 = blockIdx.x * 128, n0 = blockIdx.y * 128;
    const int g = lane >> 4, li = lane & 15;

    f32x4 acc[4][4] = {};
    const int rr = tid >> 2;
    const int cc = (tid & 3) * 8;

    for (int k0 = 0; k0 < K; k0 += 32) {
#pragma unroll
        for (int p = 0; p < 128; p += 64) {
            int r = rr + p;
            *(uint4*)&As[r][cc] = *(const uint4*)(A + (size_t)(m0 + r) * K + k0 + cc);
            *(uint4*)&Bs[r][cc] = *(const uint4*)(Bt + (size_t)(n0 + r) * K + k0 + cc);
        }
        __syncthreads();

        bf16x8 af[4], bfv[4];
#pragma unroll
        for (int mi = 0; mi < 4; mi++)
            af[mi] = *(const bf16x8*)&As[wr * 64 + mi * 16 + li][g * 8];
#pragma unroll
        for (int ni = 0; ni < 4; ni++)
            bfv[ni] = *(const bf16x8*)&Bs[wc * 64 + ni * 16 + li][g * 8];
#pragma unroll
        for (int mi = 0; mi < 4; mi++)
#pragma unroll
            for (int ni = 0; ni < 4; ni++)
                acc[mi][ni] = __builtin_amdgcn_mfma_f32_16x16x32_bf16(af[mi], bfv[ni], acc[mi][ni], 0, 0, 0);
        __syncthreads();
    }

#pragma unroll
    for (int mi = 0; mi < 4; mi++) {
        int rowb = m0 + wr * 64 + mi * 16 + g * 4;
#pragma unroll
        for (int ni = 0; ni < 4; ni++) {
            int col = n0 + wc * 64 + ni * 16 + li;
            float bv = bias[col];
#pragma unroll
            for (int r2 = 0; r2 < 4; r2++)
                Cp[(size_t)(rowb + r2) * ldc + col] = acc[mi][ni][r2] + bv;
        }
    }
}

// ---------------- fused attention: QBLK=64, 16 waves (8 heads x 2 q-groups), NZ=4 -------
// grid (64, NZ); block 1024, launch_bounds (1024,4). Round-16 proven structure; only
// change: ONE barrier per chunk. Safe: stage_write hits the buffer last READ during
// chunk c-1, already separated by chunk c-1's trailing barrier; only the post-write
// visibility barrier is needed.
__global__ __launch_bounds__(1024, 4) void attn_kernel(
    const unsigned short* __restrict__ qg, const unsigned short* __restrict__ kfb,
    const unsigned short* __restrict__ vfb,
    const unsigned short* __restrict__ bcb,
    float* __restrict__ Op, float* __restrict__ Mp, float* __restrict__ Lp,
    int KZ, int NC) {
    __shared__ _Float16 bias_s[2][128][72];   // [buf][key][q0..63], log2-domain

    const int tid  = threadIdx.x;
    const int lane = tid & 63;
    const int wv   = tid >> 6;        // 0..15
    const int w    = wv & 7;          // head
    const int qgi  = wv >> 3;         // q-group 0/1
    const int q5   = lane & 31;
    const int hi   = lane >> 5;
    const int n0   = blockIdx.x * 64;
    const int qrow = n0 + qgi * 32 + q5;
    const int qc   = qgi * 32 + q5;   // column in bias LDS
    const int z    = blockIdx.y;
    const int kz0  = z * KZ;
    const int hb   = w * kD;

    bf16x8 qf[4];
#pragma unroll
    for (int f = 0; f < 4; f++)
        qf[f] = *(const bf16x8*)(qg + (size_t)qrow * 512 + hb + f * 16 + hi * 8);

    f32x16 po[2] = {};
    float m_run = -3e38f, l_run = 0.f;   // m in log2 domain; l lane-partial

    const int sr  = tid & 63;            // staging: row 0..63 (gathered map, proven)
    const int scg = tid >> 6;            // 0..15: 8-key group
    f16x8 stg;

    auto stage_load = [&](int kbase) {
        size_t idx = (size_t)(n0 + sr) * kN + kbase + scg * 8;
        stg = *(const f16x8*)(bcb + idx);
    };
    auto stage_write = [&](int buf) {
#pragma unroll
        for (int j = 0; j < 8; j++) bias_s[buf][scg * 8 + j][sr] = stg[j];
    };

    auto kload = [&](int kpos, int f) -> bf16x8 {
        return *(const bf16x8*)(kfb + (size_t)(w * 8 + f * 2 + hi) * kKFS + ((size_t)(kpos + q5) << 3));
    };

    stage_load(kz0);
    stage_write(0);
    __syncthreads();

    for (int c = 0; c < NC; c++) {
        if (c + 1 < NC) stage_load(kz0 + (c + 1) * 128);   // async-stage: issue early
        const int cb = c & 1;
        const int kbase = kz0 + c * 128;

        bf16x8 kcur[4], knxt[4];
#pragma unroll
        for (int f = 0; f < 4; f++) kcur[f] = kload(kbase, f);

#pragma unroll
        for (int s = 0; s < 4; s++) {
            const int kpos = kbase + s * 32;
            // V loads issued early (independent of P)
            bf16x8 vb00, vb01, vb10, vb11;
            {
                const size_t v0 = (size_t)(w * 2 + 0) * kVFS + (((size_t)kpos >> 3) << 8) + ((size_t)q5 << 3);
                const size_t v1 = (size_t)(w * 2 + 1) * kVFS + (((size_t)kpos >> 3) << 8) + ((size_t)q5 << 3);
                vb00 = *(const bf16x8*)(vfb + v0 + ((size_t)hi << 8));
                vb01 = *(const bf16x8*)(vfb + v0 + ((size_t)(2 + hi) << 8));
                vb10 = *(const bf16x8*)(vfb + v1 + ((size_t)hi << 8));
                vb11 = *(const bf16x8*)(vfb + v1 + ((size_t)(2 + hi) << 8));
            }
            // prefetch next subtile's K
            if (s < 3) {
#pragma unroll
                for (int f = 0; f < 4; f++) knxt[f] = kload(kbase + (s + 1) * 32, f);
            }
            // QK^T (swapped): scores C[key][q]
            f32x16 sc = {};
#pragma unroll
            for (int f = 0; f < 4; f++)
                sc = __builtin_amdgcn_mfma_f32_32x32x16_bf16(kcur[f], qf[f], sc, 0, 0, 0);

            float v[16];
#pragma unroll
            for (int r = 0; r < 16; r++) {
                int key = (r & 3) + 8 * (r >> 2) + 4 * hi;
                v[r] = fmaf(sc[r], SCLG2, (float)bias_s[cb][s * 32 + key][qc]);   // log2 domain
            }
            // lazy rescale check: 16 independent compares, no serial max tree on common path
            const float thr = m_run + THRL2;
            int bad = 0;
#pragma unroll
            for (int r = 0; r < 16; r++) bad |= (v[r] > thr);
            if (__any(bad)) {                     // rare: compute true max + rescale
                float t8[8];
#pragma unroll
                for (int i = 0; i < 8; i++) t8[i] = fmaxf(v[2 * i], v[2 * i + 1]);
#pragma unroll
                for (int i = 0; i < 4; i++) t8[i] = fmaxf(t8[i], t8[i + 4]);
                t8[0] = fmaxf(t8[0], t8[2]); t8[1] = fmaxf(t8[1], t8[3]);
                float mx = fmaxf(t8[0], t8[1]);
                mx = fmaxf(mx, __shfl_xor(mx, 32));
                float mnew = fmaxf(m_run, mx);
                float alpha = fast_exp2(m_run - mnew);
                m_run = mnew;
                l_run *= alpha;
                po[0] *= alpha;
                po[1] *= alpha;
            }
            float p[16], s8[8];
#pragma unroll
            for (int i = 0; i < 8; i++) {
                p[2 * i]     = fast_exp2(v[2 * i] - m_run);
                p[2 * i + 1] = fast_exp2(v[2 * i + 1] - m_run);
                s8[i] = p[2 * i] + p[2 * i + 1];
            }
#pragma unroll
            for (int i = 0; i < 4; i++) s8[i] += s8[i + 4];
            l_run += (s8[0] + s8[2]) + (s8[1] + s8[3]);
            unsigned su[8], tu[8];
#pragma unroll
            for (int i = 0; i < 8; i++) su[i] = pkbf(p[2 * i], p[2 * i + 1]);
#pragma unroll
            for (int i = 0; i < 8; i++) tu[i] = __shfl_xor(su[i], 32);
            uint4 f0 = hi ? uint4{tu[2], tu[3], su[2], su[3]} : uint4{su[0], su[1], tu[0], tu[1]};
            uint4 f1 = hi ? uint4{tu[6], tu[7], su[6], su[7]} : uint4{su[4], su[5], tu[4], tu[5]};
            bf16x8 pf0 = __builtin_bit_cast(bf16x8, f0);
            bf16x8 pf1 = __builtin_bit_cast(bf16x8, f1);
            po[0] = __builtin_amdgcn_mfma_f32_32x32x16_bf16(vb00, pf0, po[0], 0, 0, 0);
            po[0] = __builtin_amdgcn_mfma_f32_32x32x16_bf16(vb01, pf1, po[0], 0, 0, 0);
            po[1] = __builtin_amdgcn_mfma_f32_32x32x16_bf16(vb10, pf0, po[1], 0, 0, 0);
            po[1] = __builtin_amdgcn_mfma_f32_32x32x16_bf16(vb11, pf1, po[1], 0, 0, 0);
            if (s < 3) {
#pragma unroll
                for (int f = 0; f < 4; f++) kcur[f] = knxt[f];
            }
        }
        if (c + 1 < NC) {
            // single barrier per chunk: the target buffer's last readers were chunk c-1,
            // already separated by that chunk's trailing barrier.
            stage_write((c + 1) & 1);
            __syncthreads();
        }
    }

    l_run += __shfl_xor(l_run, 32);
    float* ob = Op + ((((size_t)z * kN + qrow) * kH + w) << 6);
#pragma unroll
    for (int a = 0; a < 2; a++)
#pragma unroll
        for (int m = 0; m < 4; m++) {
            float4 st = {po[a][4 * m], po[a][4 * m + 1], po[a][4 * m + 2], po[a][4 * m + 3]};
            *(float4*)(ob + a * 32 + 8 * m + 4 * hi) = st;
        }
    if (lane < 32) {
        Mp[((size_t)z * kN + qrow) * kH + w] = m_run;
        Lp[((size_t)z * kN + qrow) * kH + w] = l_run;
    }
}

// ---------------- split-K combine -> xo bf16[N][Hid] (log2 domain) ----------------
__global__ __launch_bounds__(256) void combine_kernel(const float* __restrict__ Op,
                                                      const float* __restrict__ Mp,
                                                      const float* __restrict__ Lp,
                                                      unsigned short* __restrict__ xo, int NZ) {
    int idx = blockIdx.x * 256 + threadIdx.x;
    int n = idx >> 9, c = idx & 511;
    int h = c >> 6, d = c & 63;
    float m = -3e38f;
    for (int zz = 0; zz < NZ; zz++)
        m = fmaxf(m, Mp[((size_t)zz * kN + n) * kH + h]);
    float num = 0.f, den = 0.f;
    for (int zz = 0; zz < NZ; zz++) {
        float a = fast_exp2(Mp[((size_t)zz * kN + n) * kH + h] - m);
        den += a * Lp[((size_t)zz * kN + n) * kH + h];
        num += a * Op[(((size_t)zz * kN + n) * kH + h) * kD + d];
    }
    xo[idx] = f2bf(num / den);
}

// ---------------- launch ----------------
extern "C" void kernel_launch(void* const* d_in, const int* in_sizes, int n_in,
                              void* d_out, int out_size, void* d_ws, size_t ws_size,
                              hipStream_t stream) {
    const float* node = (const float*)d_in[0];
    const void*  mask = d_in[1];
    const float* tb   = (const float*)d_in[2];
    const float* W_in = (const float*)d_in[3];
    const float* b_in = (const float*)d_in[4];
    const float* Wq   = (const float*)d_in[5];
    const float* bq   = (const float*)d_in[6];
    const float* Wk   = (const float*)d_in[7];
    const float* bk   = (const float*)d_in[8];
    const float* Wv   = (const float*)d_in[9];
    const float* bv   = (const float*)d_in[10];
    const float* Wo   = (const float*)d_in[11];
    const float* bo   = (const float*)d_in[12];
    (void)in_sizes; (void)n_in; (void)out_size;

    char* ws = (char*)d_ws;
    size_t off = 0;
    auto alloc = [&](size_t bytes) {
        void* p = ws + off;
        off += (bytes + 255) & ~(size_t)255;
        return p;
    };
    unsigned short* qb   = (unsigned short*)alloc((size_t)kN * kHid * 2);
    unsigned short* kf   = (unsigned short*)alloc((size_t)64 * kKFS * 2);
    unsigned short* vf   = (unsigned short*)alloc((size_t)16 * kVFS * 2);
    unsigned short* xo   = (unsigned short*)alloc((size_t)kN * kHid * 2);
    unsigned short* bias_c = (unsigned short*)alloc((size_t)kN * kN * 2);   // 32 MB f16
    unsigned short* Wt_o   = (unsigned short*)alloc((size_t)kHid * kHid * 2);
    unsigned short* Wct    = (unsigned short*)alloc((size_t)1536 * kIn * 2);
    float* bc   = (float*)alloc(1536 * 4);
    int*   mode = (int*)alloc(256);

    size_t fixed = off;
    size_t perz = (((size_t)kN * kHid * 4 + 255) & ~(size_t)255) +
                  2 * (((size_t)kN * kH * 4 + 255) & ~(size_t)255);
    int NZ = 4;
    if (fixed + 4 * perz > ws_size) NZ = 2;
    if (fixed + 2 * perz > ws_size) NZ = 1;
    float* Op = (float*)alloc((size_t)NZ * kN * kHid * 4);
    float* Mp = (float*)alloc((size_t)NZ * kN * kH * 4);
    float* Lp = (float*)alloc((size_t)NZ * kN * kH * 4);

    // launch 1: consolidated prep (detect + bc + Wo^T + Wct, i-tiled)
    prep_kernel<<<359, 256, 0, stream>>>((const unsigned int*)mask, mode,
                                         b_in, bq, bk, bv, Wq, Wk, Wv, W_in,
                                         Wo, Wt_o, bc, Wct);
    // launch 2: fused QKV GEMM + bias compress (independent; co-scheduled)
    fused_pp_qkv_kernel<<<384 + (kN * kN) / (256 * 8), 256, 0, stream>>>(
        node, Wct, bc, qb, kf, vf, mask, tb, mode, bias_c);

    const int KZ = kN / NZ;
    attn_kernel<<<dim3(kN / 64, NZ), 1024, 0, stream>>>(
        qb, kf, vf, bias_c, Op, Mp, Lp, KZ, KZ / 128);
    combine_kernel<<<(kN * kHid) / 256, 256, 0, stream>>>(Op, Mp, Lp, xo, NZ);

    // out = xo @ Wo + bo
    gemm_out_kernel<<<dim3(kN / 128, kHid / 128), 256, 0, stream>>>(
        xo, Wt_o, bo, (float*)d_out, kN, kHid, kHid);
}

// Round 18
// 157.481 us; speedup vs baseline: 1.1773x; 1.1773x over previous
//
#include <hip/hip_runtime.h>
#include <hip/hip_bf16.h>

static constexpr int kN   = 4096;
static constexpr int kIn  = 128;
static constexpr int kHid = 512;
static constexpr int kH   = 8;
static constexpr int kD   = 64;

// padded fragment-panel strides (break power-of-2 L2 channel aliasing)
static constexpr int kKFS = 32768 + 64;    // K panel stride (elements)
static constexpr int kVFS = 131072 + 64;   // V panel stride (elements)

// exp2-domain softmax: p = 2^(sc*SCLG2 + tb*LOG2E - m2)
#define LOG2E  1.44269504f
#define SCLG2  0.18033688f      /* 0.125 * LOG2E */
#define MASKL2 (-43281.0f)      /* -30000 * LOG2E, f16-representable */
#define THRL2  11.5415603f      /* 8 * LOG2E */

typedef __bf16    bf16x8 __attribute__((ext_vector_type(8)));
typedef _Float16  f16x8  __attribute__((ext_vector_type(8)));
typedef unsigned short u16x8 __attribute__((ext_vector_type(8)));
typedef float  f32x4  __attribute__((ext_vector_type(4)));
typedef float  f32x16 __attribute__((ext_vector_type(16)));

__device__ __forceinline__ unsigned short f2bf(float f) {
    return __builtin_bit_cast(unsigned short, (__bf16)f);
}
__device__ __forceinline__ unsigned pkbf(float a, float b) {
    return (unsigned)f2bf(a) | ((unsigned)f2bf(b) << 16);
}
__device__ __forceinline__ unsigned short f2h(float f) {
    return __builtin_bit_cast(unsigned short, (_Float16)f);
}
__device__ __forceinline__ float fast_exp2(float x) {
#if __has_builtin(__builtin_amdgcn_exp2f)
    return __builtin_amdgcn_exp2f(x);
#else
    return exp2f(x);
#endif
}

// ---------------- consolidated prep: detect + bc + Wo-transpose + Wct, one launch -------
// blocks 0         : mask dtype detect
// blocks 1..6      : bc[j] = sum_k b_in[k]*Wqkv[k][j] + bqkv[j]
// blocks 7..262    : Wo transpose f32[512][512] -> bf16^T (256 tiles)
// blocks 263..1030 : Wct[j][i] (768 blocks, one i per block — proven 15us version;
//                    round-17's 96-block i-tiling starved the grid: 0.4 blocks/CU)
__global__ __launch_bounds__(256) void prep_kernel(
    const unsigned int* __restrict__ m, int* __restrict__ mode,
    const float* __restrict__ b_in,
    const float* __restrict__ bq, const float* __restrict__ bk, const float* __restrict__ bv,
    const float* __restrict__ Wq, const float* __restrict__ Wk, const float* __restrict__ Wv,
    const float* __restrict__ W_in,
    const float* __restrict__ Wo, unsigned short* __restrict__ Wt_o,
    float* __restrict__ bc, unsigned short* __restrict__ Wct) {
    const int bx = blockIdx.x;
    const int t  = threadIdx.x;
    if (bx == 0) {
        if (t >= 64) return;
        int isf = 0, isb = 0;
        for (int i = t; i < 4096; i += 64) {
            unsigned int w = m[i];
            if (w == 0x3F800000u) isf = 1;
            else if (w > 1u)      isb = 1;
        }
        unsigned long long bf = __ballot(isf != 0);
        unsigned long long bb = __ballot(isb != 0);
        if (t == 0) mode[0] = bf ? 2 : (bb ? 1 : 0);
        return;
    }
    if (bx <= 6) {
        int j = (bx - 1) * 256 + t;   // 0..1535
        const float* W = j < 512 ? Wq : (j < 1024 ? Wk : Wv);
        int jc = j & 511;
        float acc = j < 512 ? bq[jc] : (j < 1024 ? bk[jc] : bv[jc]);
        for (int k = 0; k < kHid; k++) acc = fmaf(b_in[k], W[(size_t)k * kHid + jc], acc);
        bc[j] = acc;
        return;
    }
    if (bx <= 262) {
        __shared__ float tile[32][33];
        int bx2 = bx - 7;
        int c0 = (bx2 & 15) * 32, r0 = (bx2 >> 4) * 32;
        int tx = t & 31, ty = t >> 5;   // 32 x 8
#pragma unroll
        for (int i = 0; i < 4; i++) {
            int r = ty + i * 8;
            tile[r][tx] = Wo[(size_t)(r0 + r) * kHid + c0 + tx];
        }
        __syncthreads();
#pragma unroll
        for (int i = 0; i < 4; i++) {
            int r = ty + i * 8;
            Wt_o[(size_t)(c0 + r) * kHid + r0 + tx] = f2bf(tile[tx][r]);
        }
        return;
    }
    {
        int bx3 = bx - 263;             // 0..767
        int i  = bx3 / 6;               // 0..127  (input-dim, block-uniform)
        int jg = bx3 % 6;               // 0..5
        int j  = jg * 256 + t;          // 0..1535 (lane-consecutive)
        const float* W = j < 512 ? Wq : (j < 1024 ? Wk : Wv);
        int jc = j & 511;
        const float* wrow = W_in + (size_t)i * kHid;   // W_in[i][.] (row-major [128][512])
        float acc = 0.f;
        for (int k = 0; k < kHid; k++)
            acc = fmaf(wrow[k], W[(size_t)k * kHid + jc], acc);
        Wct[(size_t)j * kIn + i] = f2bf(acc);
    }
}

// ---------------- fused: QKV GEMM (blocks 0..383) + bias compress (blocks 384..8575) ----
__global__ __launch_bounds__(256) void fused_pp_qkv_kernel(
    const float* __restrict__ Anode, const unsigned short* __restrict__ Wct,
    const float* __restrict__ bcv,
    unsigned short* __restrict__ qbp, unsigned short* __restrict__ kfp,
    unsigned short* __restrict__ vfp,
    const void* __restrict__ maskp, const float* __restrict__ tbp,
    const int* __restrict__ modep, unsigned short* __restrict__ bias_c) {
    __shared__ unsigned short As[128][40];
    __shared__ unsigned short Bs[128][40];
    const int b = blockIdx.x;
    if (b >= 384) {
        // ---- prepass branch: (mask, tb) -> f16 log2-domain bias ----
        const int mode = modep[0];
        size_t idx = ((size_t)(b - 384) * 256 + threadIdx.x) * 8;
        float tv[8];
        *(float4*)&tv[0] = *(const float4*)(tbp + idx);
        *(float4*)&tv[4] = *(const float4*)(tbp + idx + 4);
        u16x8 o;
        if (mode == 0) {
            const int* mp = (const int*)maskp;
            int4 a = *(const int4*)(mp + idx);
            int4 bb = *(const int4*)(mp + idx + 4);
            int mv[8] = {a.x, a.y, a.z, a.w, bb.x, bb.y, bb.z, bb.w};
#pragma unroll
            for (int j = 0; j < 8; j++) o[j] = f2h(mv[j] ? MASKL2 : tv[j] * LOG2E);
        } else if (mode == 1) {
            const unsigned char* mp = (const unsigned char*)maskp;
            uint2 u = *(const uint2*)(mp + idx);
#pragma unroll
            for (int j = 0; j < 4; j++) o[j] = f2h(((u.x >> (8 * j)) & 255u) ? MASKL2 : tv[j] * LOG2E);
#pragma unroll
            for (int j = 0; j < 4; j++) o[4 + j] = f2h(((u.y >> (8 * j)) & 255u) ? MASKL2 : tv[4 + j] * LOG2E);
        } else {
            const float* mp = (const float*)maskp;
            float4 a = *(const float4*)(mp + idx);
            float4 bb = *(const float4*)(mp + idx + 4);
            float mv[8] = {a.x, a.y, a.z, a.w, bb.x, bb.y, bb.z, bb.w};
#pragma unroll
            for (int j = 0; j < 8; j++) o[j] = f2h((mv[j] != 0.f) ? MASKL2 : tv[j] * LOG2E);
        }
        *(u16x8*)(bias_c + idx) = o;
        return;
    }
    // ---- QKV GEMM branch: [4096,128] @ Wct^T + bc; M=4096 N=1536 K=128 ----
    const int tid  = threadIdx.x;
    const int lane = tid & 63;
    const int wv   = tid >> 6;
    const int wr   = wv >> 1, wc = wv & 1;
    const int m0 = (b & 31) * 128, n0 = (b >> 5) * 128;
    const int g = lane >> 4, li = lane & 15;
    const int K = kIn;

    f32x4 acc[4][4] = {};
    const int rr = tid >> 2;
    const int cc = (tid & 3) * 8;

    for (int k0 = 0; k0 < K; k0 += 32) {
#pragma unroll
        for (int p = 0; p < 128; p += 64) {
            int r = rr + p;
            const float4 v0 = *(const float4*)(Anode + (size_t)(m0 + r) * K + k0 + cc);
            const float4 v1 = *(const float4*)(Anode + (size_t)(m0 + r) * K + k0 + cc + 4);
            uint4 u;
            u.x = f2bf(v0.x) | ((unsigned)f2bf(v0.y) << 16);
            u.y = f2bf(v0.z) | ((unsigned)f2bf(v0.w) << 16);
            u.z = f2bf(v1.x) | ((unsigned)f2bf(v1.y) << 16);
            u.w = f2bf(v1.z) | ((unsigned)f2bf(v1.w) << 16);
            *(uint4*)&As[r][cc] = u;
            *(uint4*)&Bs[r][cc] = *(const uint4*)(Wct + (size_t)(n0 + r) * K + k0 + cc);
        }
        __syncthreads();

        bf16x8 af[4], bfv[4];
#pragma unroll
        for (int mi = 0; mi < 4; mi++)
            af[mi] = *(const bf16x8*)&As[wr * 64 + mi * 16 + li][g * 8];
#pragma unroll
        for (int ni = 0; ni < 4; ni++)
            bfv[ni] = *(const bf16x8*)&Bs[wc * 64 + ni * 16 + li][g * 8];
#pragma unroll
        for (int mi = 0; mi < 4; mi++)
#pragma unroll
            for (int ni = 0; ni < 4; ni++)
                acc[mi][ni] = __builtin_amdgcn_mfma_f32_16x16x32_bf16(af[mi], bfv[ni], acc[mi][ni], 0, 0, 0);
        __syncthreads();
    }

#pragma unroll
    for (int mi = 0; mi < 4; mi++) {
        int rowb = m0 + wr * 64 + mi * 16 + g * 4;
#pragma unroll
        for (int ni = 0; ni < 4; ni++) {
            int col = n0 + wc * 64 + ni * 16 + li;
            float bv = bcv[col];
            if (col < 512) {
#pragma unroll
                for (int r2 = 0; r2 < 4; r2++)
                    qbp[(size_t)(rowb + r2) * 512 + col] = f2bf(acc[mi][ni][r2] + bv);
            } else if (col < 1024) {
                int d = col - 512;
                size_t base = (size_t)(d >> 3) * kKFS + (size_t)(d & 7);
#pragma unroll
                for (int r2 = 0; r2 < 4; r2++)
                    kfp[base + ((size_t)(rowb + r2) << 3)] = f2bf(acc[mi][ni][r2] + bv);
            } else {
                int d = col - 1024;
                size_t base = (size_t)(d >> 5) * kVFS + ((size_t)(rowb >> 3) << 8) +
                              ((size_t)(d & 31) << 3) + (size_t)(rowb & 7);
                ushort4 st;
                st.x = f2bf(acc[mi][ni][0] + bv);
                st.y = f2bf(acc[mi][ni][1] + bv);
                st.z = f2bf(acc[mi][ni][2] + bv);
                st.w = f2bf(acc[mi][ni][3] + bv);
                *(ushort4*)(vfp + base) = st;
            }
        }
    }
}

// ---------------- GEMM: C[M,N] = A[M,K] @ Bt[N,K]^T + bias (f32 out) ----------------
__global__ __launch_bounds__(256) void gemm_out_kernel(const unsigned short* __restrict__ A,
                                                       const unsigned short* __restrict__ Bt,
                                                       const float* __restrict__ bias,
                                                       float* __restrict__ Cp,
                                                       int M, int K, int ldc) {
    __shared__ unsigned short As[128][40];
    __shared__ unsigned short Bs[128][40];
    const int tid  = threadIdx.x;
    const int lane = tid & 63;
    const int wv   = tid >> 6;
    const int wr   = wv >> 1, wc = wv & 1;
    const int m0 = blockIdx.x * 128, n0 = blockIdx.y * 128;
    const int g = lane >> 4, li = lane & 15;

    f32x4 acc[4][4] = {};
    const int rr = tid >> 2;
    const int cc = (tid & 3) * 8;

    for (int k0 = 0; k0 < K; k0 += 32) {
#pragma unroll
        for (int p = 0; p < 128; p += 64) {
            int r = rr + p;
            *(uint4*)&As[r][cc] = *(const uint4*)(A + (size_t)(m0 + r) * K + k0 + cc);
            *(uint4*)&Bs[r][cc] = *(const uint4*)(Bt + (size_t)(n0 + r) * K + k0 + cc);
        }
        __syncthreads();

        bf16x8 af[4], bfv[4];
#pragma unroll
        for (int mi = 0; mi < 4; mi++)
            af[mi] = *(const bf16x8*)&As[wr * 64 + mi * 16 + li][g * 8];
#pragma unroll
        for (int ni = 0; ni < 4; ni++)
            bfv[ni] = *(const bf16x8*)&Bs[wc * 64 + ni * 16 + li][g * 8];
#pragma unroll
        for (int mi = 0; mi < 4; mi++)
#pragma unroll
            for (int ni = 0; ni < 4; ni++)
                acc[mi][ni] = __builtin_amdgcn_mfma_f32_16x16x32_bf16(af[mi], bfv[ni], acc[mi][ni], 0, 0, 0);
        __syncthreads();
    }

#pragma unroll
    for (int mi = 0; mi < 4; mi++) {
        int rowb = m0 + wr * 64 + mi * 16 + g * 4;
#pragma unroll
        for (int ni = 0; ni < 4; ni++) {
            int col = n0 + wc * 64 + ni * 16 + li;
            float bv = bias[col];
#pragma unroll
            for (int r2 = 0; r2 < 4; r2++)
                Cp[(size_t)(rowb + r2) * ldc + col] = acc[mi][ni][r2] + bv;
        }
    }
}

// ---------------- fused attention: QBLK=64, 16 waves (8 heads x 2 q-groups), NZ=4 -------
// grid (64, NZ); block 1024, launch_bounds (1024,4). Proven structure (92us, no spills):
// f16 double-buffered bias LDS, gathered staging, lazy rescale, single barrier per chunk.
__global__ __launch_bounds__(1024, 4) void attn_kernel(
    const unsigned short* __restrict__ qg, const unsigned short* __restrict__ kfb,
    const unsigned short* __restrict__ vfb,
    const unsigned short* __restrict__ bcb,
    float* __restrict__ Op, float* __restrict__ Mp, float* __restrict__ Lp,
    int KZ, int NC) {
    __shared__ _Float16 bias_s[2][128][72];   // [buf][key][q0..63], log2-domain

    const int tid  = threadIdx.x;
    const int lane = tid & 63;
    const int wv   = tid >> 6;        // 0..15
    const int w    = wv & 7;          // head
    const int qgi  = wv >> 3;         // q-group 0/1
    const int q5   = lane & 31;
    const int hi   = lane >> 5;
    const int n0   = blockIdx.x * 64;
    const int qrow = n0 + qgi * 32 + q5;
    const int qc   = qgi * 32 + q5;   // column in bias LDS
    const int z    = blockIdx.y;
    const int kz0  = z * KZ;
    const int hb   = w * kD;

    bf16x8 qf[4];
#pragma unroll
    for (int f = 0; f < 4; f++)
        qf[f] = *(const bf16x8*)(qg + (size_t)qrow * 512 + hb + f * 16 + hi * 8);

    f32x16 po[2] = {};
    float m_run = -3e38f, l_run = 0.f;   // m in log2 domain; l lane-partial

    const int sr  = tid & 63;            // staging: row 0..63 (gathered map, proven)
    const int scg = tid >> 6;            // 0..15: 8-key group
    f16x8 stg;

    auto stage_load = [&](int kbase) {
        size_t idx = (size_t)(n0 + sr) * kN + kbase + scg * 8;
        stg = *(const f16x8*)(bcb + idx);
    };
    auto stage_write = [&](int buf) {
#pragma unroll
        for (int j = 0; j < 8; j++) bias_s[buf][scg * 8 + j][sr] = stg[j];
    };

    auto kload = [&](int kpos, int f) -> bf16x8 {
        return *(const bf16x8*)(kfb + (size_t)(w * 8 + f * 2 + hi) * kKFS + ((size_t)(kpos + q5) << 3));
    };

    stage_load(kz0);
    stage_write(0);
    __syncthreads();

    for (int c = 0; c < NC; c++) {
        if (c + 1 < NC) stage_load(kz0 + (c + 1) * 128);   // async-stage: issue early
        const int cb = c & 1;
        const int kbase = kz0 + c * 128;

        bf16x8 kcur[4], knxt[4];
#pragma unroll
        for (int f = 0; f < 4; f++) kcur[f] = kload(kbase, f);

#pragma unroll
        for (int s = 0; s < 4; s++) {
            const int kpos = kbase + s * 32;
            // V loads issued early (independent of P)
            bf16x8 vb00, vb01, vb10, vb11;
            {
                const size_t v0 = (size_t)(w * 2 + 0) * kVFS + (((size_t)kpos >> 3) << 8) + ((size_t)q5 << 3);
                const size_t v1 = (size_t)(w * 2 + 1) * kVFS + (((size_t)kpos >> 3) << 8) + ((size_t)q5 << 3);
                vb00 = *(const bf16x8*)(vfb + v0 + ((size_t)hi << 8));
                vb01 = *(const bf16x8*)(vfb + v0 + ((size_t)(2 + hi) << 8));
                vb10 = *(const bf16x8*)(vfb + v1 + ((size_t)hi << 8));
                vb11 = *(const bf16x8*)(vfb + v1 + ((size_t)(2 + hi) << 8));
            }
            // prefetch next subtile's K
            if (s < 3) {
#pragma unroll
                for (int f = 0; f < 4; f++) knxt[f] = kload(kbase + (s + 1) * 32, f);
            }
            // QK^T (swapped): scores C[key][q]
            f32x16 sc = {};
#pragma unroll
            for (int f = 0; f < 4; f++)
                sc = __builtin_amdgcn_mfma_f32_32x32x16_bf16(kcur[f], qf[f], sc, 0, 0, 0);

            float v[16];
#pragma unroll
            for (int r = 0; r < 16; r++) {
                int key = (r & 3) + 8 * (r >> 2) + 4 * hi;
                v[r] = fmaf(sc[r], SCLG2, (float)bias_s[cb][s * 32 + key][qc]);   // log2 domain
            }
            // lazy rescale check: 16 independent compares, no serial max tree on common path
            const float thr = m_run + THRL2;
            int bad = 0;
#pragma unroll
            for (int r = 0; r < 16; r++) bad |= (v[r] > thr);
            if (__any(bad)) {                     // rare: compute true max + rescale
                float t8[8];
#pragma unroll
                for (int i = 0; i < 8; i++) t8[i] = fmaxf(v[2 * i], v[2 * i + 1]);
#pragma unroll
                for (int i = 0; i < 4; i++) t8[i] = fmaxf(t8[i], t8[i + 4]);
                t8[0] = fmaxf(t8[0], t8[2]); t8[1] = fmaxf(t8[1], t8[3]);
                float mx = fmaxf(t8[0], t8[1]);
                mx = fmaxf(mx, __shfl_xor(mx, 32));
                float mnew = fmaxf(m_run, mx);
                float alpha = fast_exp2(m_run - mnew);
                m_run = mnew;
                l_run *= alpha;
                po[0] *= alpha;
                po[1] *= alpha;
            }
            float p[16], s8[8];
#pragma unroll
            for (int i = 0; i < 8; i++) {
                p[2 * i]     = fast_exp2(v[2 * i] - m_run);
                p[2 * i + 1] = fast_exp2(v[2 * i + 1] - m_run);
                s8[i] = p[2 * i] + p[2 * i + 1];
            }
#pragma unroll
            for (int i = 0; i < 4; i++) s8[i] += s8[i + 4];
            l_run += (s8[0] + s8[2]) + (s8[1] + s8[3]);
            unsigned su[8], tu[8];
#pragma unroll
            for (int i = 0; i < 8; i++) su[i] = pkbf(p[2 * i], p[2 * i + 1]);
#pragma unroll
            for (int i = 0; i < 8; i++) tu[i] = __shfl_xor(su[i], 32);
            uint4 f0 = hi ? uint4{tu[2], tu[3], su[2], su[3]} : uint4{su[0], su[1], tu[0], tu[1]};
            uint4 f1 = hi ? uint4{tu[6], tu[7], su[6], su[7]} : uint4{su[4], su[5], tu[4], tu[5]};
            bf16x8 pf0 = __builtin_bit_cast(bf16x8, f0);
            bf16x8 pf1 = __builtin_bit_cast(bf16x8, f1);
            po[0] = __builtin_amdgcn_mfma_f32_32x32x16_bf16(vb00, pf0, po[0], 0, 0, 0);
            po[0] = __builtin_amdgcn_mfma_f32_32x32x16_bf16(vb01, pf1, po[0], 0, 0, 0);
            po[1] = __builtin_amdgcn_mfma_f32_32x32x16_bf16(vb10, pf0, po[1], 0, 0, 0);
            po[1] = __builtin_amdgcn_mfma_f32_32x32x16_bf16(vb11, pf1, po[1], 0, 0, 0);
            if (s < 3) {
#pragma unroll
                for (int f = 0; f < 4; f++) kcur[f] = knxt[f];
            }
        }
        if (c + 1 < NC) {
            // single barrier per chunk: the target buffer's last readers were chunk c-1,
            // already separated by that chunk's trailing barrier.
            stage_write((c + 1) & 1);
            __syncthreads();
        }
    }

    l_run += __shfl_xor(l_run, 32);
    float* ob = Op + ((((size_t)z * kN + qrow) * kH + w) << 6);
#pragma unroll
    for (int a = 0; a < 2; a++)
#pragma unroll
        for (int m = 0; m < 4; m++) {
            float4 st = {po[a][4 * m], po[a][4 * m + 1], po[a][4 * m + 2], po[a][4 * m + 3]};
            *(float4*)(ob + a * 32 + 8 * m + 4 * hi) = st;
        }
    if (lane < 32) {
        Mp[((size_t)z * kN + qrow) * kH + w] = m_run;
        Lp[((size_t)z * kN + qrow) * kH + w] = l_run;
    }
}

// ---------------- split-K combine -> xo bf16[N][Hid] (log2 domain) ----------------
__global__ __launch_bounds__(256) void combine_kernel(const float* __restrict__ Op,
                                                      const float* __restrict__ Mp,
                                                      const float* __restrict__ Lp,
                                                      unsigned short* __restrict__ xo, int NZ) {
    int idx = blockIdx.x * 256 + threadIdx.x;
    int n = idx >> 9, c = idx & 511;
    int h = c >> 6, d = c & 63;
    float m = -3e38f;
    for (int zz = 0; zz < NZ; zz++)
        m = fmaxf(m, Mp[((size_t)zz * kN + n) * kH + h]);
    float num = 0.f, den = 0.f;
    for (int zz = 0; zz < NZ; zz++) {
        float a = fast_exp2(Mp[((size_t)zz * kN + n) * kH + h] - m);
        den += a * Lp[((size_t)zz * kN + n) * kH + h];
        num += a * Op[(((size_t)zz * kN + n) * kH + h) * kD + d];
    }
    xo[idx] = f2bf(num / den);
}

// ---------------- launch ----------------
extern "C" void kernel_launch(void* const* d_in, const int* in_sizes, int n_in,
                              void* d_out, int out_size, void* d_ws, size_t ws_size,
                              hipStream_t stream) {
    const float* node = (const float*)d_in[0];
    const void*  mask = d_in[1];
    const float* tb   = (const float*)d_in[2];
    const float* W_in = (const float*)d_in[3];
    const float* b_in = (const float*)d_in[4];
    const float* Wq   = (const float*)d_in[5];
    const float* bq   = (const float*)d_in[6];
    const float* Wk   = (const float*)d_in[7];
    const float* bk   = (const float*)d_in[8];
    const float* Wv   = (const float*)d_in[9];
    const float* bv   = (const float*)d_in[10];
    const float* Wo   = (const float*)d_in[11];
    const float* bo   = (const float*)d_in[12];
    (void)in_sizes; (void)n_in; (void)out_size;

    char* ws = (char*)d_ws;
    size_t off = 0;
    auto alloc = [&](size_t bytes) {
        void* p = ws + off;
        off += (bytes + 255) & ~(size_t)255;
        return p;
    };
    unsigned short* qb   = (unsigned short*)alloc((size_t)kN * kHid * 2);
    unsigned short* kf   = (unsigned short*)alloc((size_t)64 * kKFS * 2);
    unsigned short* vf   = (unsigned short*)alloc((size_t)16 * kVFS * 2);
    unsigned short* xo   = (unsigned short*)alloc((size_t)kN * kHid * 2);
    unsigned short* bias_c = (unsigned short*)alloc((size_t)kN * kN * 2);   // 32 MB f16
    unsigned short* Wt_o   = (unsigned short*)alloc((size_t)kHid * kHid * 2);
    unsigned short* Wct    = (unsigned short*)alloc((size_t)1536 * kIn * 2);
    float* bc   = (float*)alloc(1536 * 4);
    int*   mode = (int*)alloc(256);

    size_t fixed = off;
    size_t perz = (((size_t)kN * kHid * 4 + 255) & ~(size_t)255) +
                  2 * (((size_t)kN * kH * 4 + 255) & ~(size_t)255);
    int NZ = 4;
    if (fixed + 4 * perz > ws_size) NZ = 2;
    if (fixed + 2 * perz > ws_size) NZ = 1;
    float* Op = (float*)alloc((size_t)NZ * kN * kHid * 4);
    float* Mp = (float*)alloc((size_t)NZ * kN * kH * 4);
    float* Lp = (float*)alloc((size_t)NZ * kN * kH * 4);

    // launch 1: consolidated prep (detect + bc + Wo^T + Wct, 1031 blocks — proven)
    prep_kernel<<<1031, 256, 0, stream>>>((const unsigned int*)mask, mode,
                                          b_in, bq, bk, bv, Wq, Wk, Wv, W_in,
                                          Wo, Wt_o, bc, Wct);
    // launch 2: fused QKV GEMM + bias compress (independent; co-scheduled)
    fused_pp_qkv_kernel<<<384 + (kN * kN) / (256 * 8), 256, 0, stream>>>(
        node, Wct, bc, qb, kf, vf, mask, tb, mode, bias_c);

    const int KZ = kN / NZ;
    attn_kernel<<<dim3(kN / 64, NZ), 1024, 0, stream>>>(
        qb, kf, vf, bias_c, Op, Mp, Lp, KZ, KZ / 128);
    combine_kernel<<<(kN * kHid) / 256, 256, 0, stream>>>(Op, Mp, Lp, xo, NZ);

    // out = xo @ Wo + bo
    gemm_out_kernel<<<dim3(kN / 128, kHid / 128), 256, 0, stream>>>(
        xo, Wt_o, bo, (float*)d_out, kN, kHid, kHid);
}